// Round 4
// baseline (1235.808 us; speedup 1.0000x reference)
//
#include <hip/hip_runtime.h>

typedef __attribute__((ext_vector_type(16))) float f32x16;
typedef unsigned long long u64;

// ---------------------------------------------------------------------------
// Quantize x (f32, M x 128 row-major) -> fp8 e4m3fn in A-fragment-major pack:
//   ap u64 index = (m/32)*512 + kk*64 + lane,  lane = h*32 + r  (h=0..1, r=0..31)
//   holds x[m32*32 + r][kk*16 + h*8 .. +8]   (kk = 0..7, K=128)
// ---------------------------------------------------------------------------
__global__ void quant_x_pack(const float* __restrict__ x,
                             const float* __restrict__ scale,
                             u64* __restrict__ ap, int total) {
    int t = blockIdx.x * blockDim.x + threadIdx.x;   // total = M*16
    if (t >= total) return;
    float s = scale[0];
    int lane = t & 63;
    int kk   = (t >> 6) & 7;
    int m32  = t >> 9;
    int r = lane & 31, h = lane >> 5;
    const float* src = x + ((size_t)(m32 * 32 + r)) * 128 + kk * 16 + h * 8;
    float4 a = *reinterpret_cast<const float4*>(src);
    float4 b = *reinterpret_cast<const float4*>(src + 4);
    int lo = 0, hi = 0;
    lo = __builtin_amdgcn_cvt_pk_fp8_f32(a.x * s, a.y * s, lo, false);
    lo = __builtin_amdgcn_cvt_pk_fp8_f32(a.z * s, a.w * s, lo, true);
    hi = __builtin_amdgcn_cvt_pk_fp8_f32(b.x * s, b.y * s, hi, false);
    hi = __builtin_amdgcn_cvt_pk_fp8_f32(b.z * s, b.w * s, hi, true);
    ap[t] = ((u64)(unsigned int)hi << 32) | (unsigned int)lo;
}

// ---------------------------------------------------------------------------
// Quantize y (f32, 128 x N row-major) -> fp8 in B-fragment-major pack:
//   bp u64 index = (n/32)*512 + kk*64 + lane,  lane = h*32 + c
//   holds y[kk*16 + h*8 .. +8][n32*32 + c]
// ---------------------------------------------------------------------------
__global__ void quant_y_pack(const float* __restrict__ y,
                             const float* __restrict__ scale,
                             u64* __restrict__ bp, int N, int total) {
    int t = blockIdx.x * blockDim.x + threadIdx.x;   // total = N*16
    if (t >= total) return;
    float s = scale[0];
    int lane = t & 63;
    int kk   = (t >> 6) & 7;
    int n32  = t >> 9;
    int c = lane & 31, h = lane >> 5;
    const float* src = y + (size_t)(kk * 16 + h * 8) * N + n32 * 32 + c;
    float v[8];
#pragma unroll
    for (int j = 0; j < 8; ++j) v[j] = src[(size_t)j * N] * s;
    int lo = 0, hi = 0;
    lo = __builtin_amdgcn_cvt_pk_fp8_f32(v[0], v[1], lo, false);
    lo = __builtin_amdgcn_cvt_pk_fp8_f32(v[2], v[3], lo, true);
    hi = __builtin_amdgcn_cvt_pk_fp8_f32(v[4], v[5], hi, false);
    hi = __builtin_amdgcn_cvt_pk_fp8_f32(v[6], v[7], hi, true);
    bp[t] = ((u64)(unsigned int)hi << 32) | (unsigned int)lo;
}

// ---------------------------------------------------------------------------
// GEMM: [M x 128]fp8 @ [128 x N]fp8 -> f32 * inv.
// Block = 32 rows x FULL N (4096 cols): 1024 threads = 16 waves side by side,
// each wave a 32x256 strip = 8 n-frags of mfma_f32_32x32x16_fp8_fp8, K=128 in
// registers. Each block writes a perfectly CONTIGUOUS 512 KB output region
// (16 waves fill whole 16 KB rows); XCD swizzle gives each XCD a linear
// 128 MB write sweep -> memset-like HBM row-buffer locality (round-4 theory:
// the 12% gap vs fillBuffer BW was scattered 512B write granules).
//   A/B frag: lane = h*32 + r holds 8 fp8 at [r][kk*16 + h*8..+8]
//   C/D: col = lane&31, row = (reg&3) + 8*(reg>>2) + 4*(lane>>5)  [m74/m101]
// Output stores NONTEMPORAL (round-3 win: don't evict fp8 panels from L2).
// ---------------------------------------------------------------------------
__global__ __launch_bounds__(1024) void gemm_fp8_kernel(
    const u64* __restrict__ ap, const u64* __restrict__ bp,
    const float* __restrict__ xs, const float* __restrict__ ys,
    float* __restrict__ out, int M, int N) {
    int nband = gridDim.x;           // M/32, multiple of 8
    int cpx   = nband >> 3;
    int bid   = blockIdx.x;
    int band  = (bid & 7) * cpx + (bid >> 3);   // bijective XCD swizzle

    int wid  = threadIdx.x >> 6;     // 0..15
    int lane = threadIdx.x & 63;
    int m0   = band * 32;
    int n0   = wid * (N >> 4);       // 256-col strip per wave (N=4096)

    float inv = 1.0f / (xs[0] * ys[0]);

    const u64* abase = ap + (size_t)(m0 >> 5) * 512 + lane;   // + kk*64
    const u64* bbase = bp + (size_t)(n0 >> 5) * 512 + lane;   // + nf*512 + kk*64

    f32x16 acc[8] = {};

#pragma unroll
    for (int kk = 0; kk < 8; ++kk) {
        long a = (long)abase[kk * 64];
#pragma unroll
        for (int nf = 0; nf < 8; ++nf) {
            long b = (long)bbase[(size_t)nf * 512 + kk * 64];
            acc[nf] = __builtin_amdgcn_mfma_f32_32x32x16_fp8_fp8(a, b, acc[nf], 0, 0, 0);
        }
    }

    int col = lane & 31;
    int h4  = (lane >> 5) * 4;
    // rg-outer / nf-inner: consecutive stores write adjacent 128B lines of the
    // same two output rows -> long contiguous bursts per wave.
#pragma unroll
    for (int rg = 0; rg < 16; ++rg) {
        int row = (rg & 3) + 8 * (rg >> 2) + h4;
        float* o = out + (size_t)(m0 + row) * N + n0 + col;
#pragma unroll
        for (int nf = 0; nf < 8; ++nf)
            __builtin_nontemporal_store(acc[nf][rg] * inv, o + nf * 32);
    }
}

extern "C" void kernel_launch(void* const* d_in, const int* in_sizes, int n_in,
                              void* d_out, int out_size, void* d_ws, size_t ws_size,
                              hipStream_t stream) {
    const float* x  = (const float*)d_in[0];   // (B,S,K) f32
    const float* y  = (const float*)d_in[1];   // (K,N)   f32
    const float* xs = (const float*)d_in[2];   // scalar
    const float* ys = (const float*)d_in[3];   // scalar
    float* out = (float*)d_out;

    const int K = 128;
    int M = in_sizes[0] / K;   // 65536
    int N = in_sizes[1] / K;   // 4096

    u64* ap = (u64*)d_ws;                      // M*K bytes
    u64* bp = ap + (size_t)M * K / 8;          // K*N bytes

    int tx = M * (K / 8);
    quant_x_pack<<<(tx + 255) / 256, 256, 0, stream>>>(x, xs, ap, tx);

    int ty = N * (K / 8);
    quant_y_pack<<<(ty + 255) / 256, 256, 0, stream>>>(y, ys, bp, N, ty);

    int grid = M / 32;                         // 2048 bands, %8 == 0
    gemm_fp8_kernel<<<grid, 1024, 0, stream>>>(ap, bp, xs, ys, out, M, N);
}

// Round 5
// 189.257 us; speedup vs baseline: 6.5298x; 6.5298x over previous
//
#include <hip/hip_runtime.h>

typedef __attribute__((ext_vector_type(16))) float f32x16;
typedef unsigned long long u64;

// ---------------------------------------------------------------------------
// Fused quantize of x and y -> fp8 e4m3fn in fragment-major packs.
//   x: (M x 128 row-major) -> ap: u64 idx = (m/32)*512 + kk*64 + lane,
//      lane = h*32 + r holds x[m32*32+r][kk*16+h*8 .. +8]
//   y: (128 x N row-major) -> bp: u64 idx = (n/32)*512 + kk*64 + lane,
//      lane = h*32 + c holds y[kk*16+h*8 .. +8][n32*32+c]
// One kernel launch for both (saves serialized launch overhead).
// ---------------------------------------------------------------------------
__global__ void quant_pack_all(const float* __restrict__ x,
                               const float* __restrict__ y,
                               const float* __restrict__ xs,
                               const float* __restrict__ ys,
                               u64* __restrict__ ap, u64* __restrict__ bp,
                               int N, int tx, int total) {
    int t = blockIdx.x * blockDim.x + threadIdx.x;
    if (t >= total) return;
    if (t < tx) {
        float s = xs[0];
        int lane = t & 63;
        int kk   = (t >> 6) & 7;
        int m32  = t >> 9;
        int r = lane & 31, h = lane >> 5;
        const float* src = x + ((size_t)(m32 * 32 + r)) * 128 + kk * 16 + h * 8;
        float4 a = *reinterpret_cast<const float4*>(src);
        float4 b = *reinterpret_cast<const float4*>(src + 4);
        int lo = 0, hi = 0;
        lo = __builtin_amdgcn_cvt_pk_fp8_f32(a.x * s, a.y * s, lo, false);
        lo = __builtin_amdgcn_cvt_pk_fp8_f32(a.z * s, a.w * s, lo, true);
        hi = __builtin_amdgcn_cvt_pk_fp8_f32(b.x * s, b.y * s, hi, false);
        hi = __builtin_amdgcn_cvt_pk_fp8_f32(b.z * s, b.w * s, hi, true);
        ap[t] = ((u64)(unsigned int)hi << 32) | (unsigned int)lo;
    } else {
        t -= tx;
        float s = ys[0];
        int lane = t & 63;
        int kk   = (t >> 6) & 7;
        int n32  = t >> 9;
        int c = lane & 31, h = lane >> 5;
        const float* src = y + (size_t)(kk * 16 + h * 8) * N + n32 * 32 + c;
        float v[8];
#pragma unroll
        for (int j = 0; j < 8; ++j) v[j] = src[(size_t)j * N] * s;
        int lo = 0, hi = 0;
        lo = __builtin_amdgcn_cvt_pk_fp8_f32(v[0], v[1], lo, false);
        lo = __builtin_amdgcn_cvt_pk_fp8_f32(v[2], v[3], lo, true);
        hi = __builtin_amdgcn_cvt_pk_fp8_f32(v[4], v[5], hi, false);
        hi = __builtin_amdgcn_cvt_pk_fp8_f32(v[6], v[7], hi, true);
        bp[t] = ((u64)(unsigned int)hi << 32) | (unsigned int)lo;
    }
}

// ---------------------------------------------------------------------------
// GEMM: [M x 128]fp8 @ [128 x N]fp8 -> f32 * inv.
// Block = 32 rows x 512 cols, 256 threads = 4 waves SIDE BY SIDE, each wave a
// 32x128 strip = 4 n-frags of mfma_f32_32x32x16_fp8_fp8. K=128 in registers,
// no LDS. Same register budget as the proven round-3 kernel (acc = 64 f32).
// Round-4 spill lesson: 1024-thread blocks forced VGPR=64 + scratch thrash
// (6.5 GB traffic). Stay at 256 threads.
// Write locality: per output row a block writes a contiguous 2 KB; XCD
// swizzle maps consecutive blocks of one XCD bx-fast -> each XCD sweeps a
// linear 128 MB output region (write-burst theory, clean test).
//   A/B frag: lane = h*32 + r holds 8 fp8 at [r][kk*16 + h*8..+8]
//   C/D: col = lane&31, row = (reg&3) + 8*(reg>>2) + 4*(lane>>5)  [m74/m101]
// Output stores NONTEMPORAL (round-3 win: don't evict fp8 panels from L2).
// ---------------------------------------------------------------------------
__global__ __launch_bounds__(256) void gemm_fp8_kernel(
    const u64* __restrict__ ap, const u64* __restrict__ bp,
    const float* __restrict__ xs, const float* __restrict__ ys,
    float* __restrict__ out, int M, int N, int nb) {
    int nwg = gridDim.x;             // multiple of 8
    int cpx = nwg >> 3;
    int bid = blockIdx.x;
    int swz = (bid & 7) * cpx + (bid >> 3);   // bijective XCD swizzle
    int bx  = swz % nb;                        // bx-fast: linear write sweep
    int by  = swz / nb;

    int wid  = threadIdx.x >> 6;     // 0..3
    int lane = threadIdx.x & 63;
    int m0   = by * 32;
    int n0   = bx * 512 + wid * 128;

    float inv = 1.0f / (xs[0] * ys[0]);

    const u64* abase = ap + (size_t)(m0 >> 5) * 512 + lane;   // + kk*64
    const u64* bbase = bp + (size_t)(n0 >> 5) * 512 + lane;   // + nf*512 + kk*64

    f32x16 acc[4] = {};

#pragma unroll
    for (int kk = 0; kk < 8; ++kk) {
        long a = (long)abase[kk * 64];
#pragma unroll
        for (int nf = 0; nf < 4; ++nf) {
            long b = (long)bbase[(size_t)nf * 512 + kk * 64];
            acc[nf] = __builtin_amdgcn_mfma_f32_32x32x16_fp8_fp8(a, b, acc[nf], 0, 0, 0);
        }
    }

    int col = lane & 31;
    int h4  = (lane >> 5) * 4;
    // rg-outer / nf-inner: per rg the wave writes 4 adjacent 128B lines of one
    // row (512B burst); 4 waves cover a contiguous 2KB row segment.
#pragma unroll
    for (int rg = 0; rg < 16; ++rg) {
        int row = (rg & 3) + 8 * (rg >> 2) + h4;
        float* o = out + (size_t)(m0 + row) * N + n0 + col;
#pragma unroll
        for (int nf = 0; nf < 4; ++nf)
            __builtin_nontemporal_store(acc[nf][rg] * inv, o + nf * 32);
    }
}

extern "C" void kernel_launch(void* const* d_in, const int* in_sizes, int n_in,
                              void* d_out, int out_size, void* d_ws, size_t ws_size,
                              hipStream_t stream) {
    const float* x  = (const float*)d_in[0];   // (B,S,K) f32
    const float* y  = (const float*)d_in[1];   // (K,N)   f32
    const float* xs = (const float*)d_in[2];   // scalar
    const float* ys = (const float*)d_in[3];   // scalar
    float* out = (float*)d_out;

    const int K = 128;
    int M = in_sizes[0] / K;   // 65536
    int N = in_sizes[1] / K;   // 4096

    u64* ap = (u64*)d_ws;                      // M*K bytes
    u64* bp = ap + (size_t)M * K / 8;          // K*N bytes

    int tx = M * (K / 8);                      // 1048576 (multiple of 256)
    int ty = N * (K / 8);                      // 65536
    int total = tx + ty;
    quant_pack_all<<<(total + 255) / 256, 256, 0, stream>>>(x, y, xs, ys, ap, bp,
                                                            N, tx, total);

    int nb = N / 512;                          // 8
    int grid = (M / 32) * nb;                  // 16384, %8 == 0
    gemm_fp8_kernel<<<grid, 256, 0, stream>>>(ap, bp, xs, ys, out, M, N, nb);
}